// Round 5
// baseline (47.836 us; speedup 1.0000x reference)
//
#include <hip/hip_runtime.h>
#include <stdint.h>

#define GCOUNT 8192
#define BATCH 2
#define IMGH 256
#define IMGW 256
#define TILE 8
#define TILES_X (IMGW / TILE)   // 32
#define TILES_Y (IMGH / TILE)   // 32
#define MAXLIST 512             // avg ~112 survivors per 8x8 tile; ~4x headroom

// Barrier that does NOT drain vmcnt (unlike __syncthreads): LDS ordering only.
// Keeps the staging global-loads in flight across the whole sort phase.
#define LDS_BAR() do { asm volatile("s_waitcnt lgkmcnt(0)" ::: "memory"); \
                       __builtin_amdgcn_s_barrier(); } while (0)

// ---------------------------------------------------------------------------
// Kernel 1: per-Gaussian prep. Repack into composite-ready form + conservative
// 8px-tile bbox + stable sort key (depth_bits<<13 | idx): depths positive so
// IEEE bits are order-preserving; low 13 bits = stable tie-break == jnp.argsort.
// ---------------------------------------------------------------------------
__global__ __launch_bounds__(256) void prep(
    const float* __restrict__ means, const float* __restrict__ conics,
    const float* __restrict__ colors, const float* __restrict__ opac,
    const float* __restrict__ depths,
    float4* __restrict__ gdat,            // [B*G*2]: (mx,my,-a/2,-b) (-c/2,op,r,g)
    float* __restrict__ gblue,            // [B*G]
    uint32_t* __restrict__ gbbox,         // [B*G]
    unsigned long long* __restrict__ gkey)// [B*G]
{
    const int t = blockIdx.x * 256 + threadIdx.x;
    if (t >= BATCH * GCOUNT) return;
    const int g = t & (GCOUNT - 1);

    const float mx  = means[t * 2 + 0];
    const float my  = means[t * 2 + 1];
    const float ca  = conics[t * 3 + 0];
    const float cb  = conics[t * 3 + 1];
    const float cc  = conics[t * 3 + 2];
    const float cr  = colors[t * 3 + 0];
    const float cg  = colors[t * 3 + 1];
    const float cbl = colors[t * 3 + 2];
    const float op  = opac[t];
    const float dep = depths[t];

    // alpha >= 1/255  <=>  Q(d) <= ln(255*op) = tt  (op >= 0.05 so tt > 0)
    const float tt  = __logf(255.0f * op);
    const float det = ca * cc - cb * cb;   // >= 0.75*a*c > 0
    const float inv = 2.0f * tt / det;
    const float dxm = sqrtf(inv * cc) + 1.0f;  // +1px safety pad
    const float dym = sqrtf(inv * ca) + 1.0f;

    int x0 = max(0, (int)floorf((mx - dxm) * (1.0f / TILE)));
    int x1 = min(TILES_X - 1, (int)floorf((mx + dxm) * (1.0f / TILE)));
    int y0 = max(0, (int)floorf((my - dym) * (1.0f / TILE)));
    int y1 = min(TILES_Y - 1, (int)floorf((my + dym) * (1.0f / TILE)));
    uint32_t bb;
    if (x1 < x0 || y1 < y0)
        bb = 0xFFu;  // x0=255 never matches (tx <= 31)
    else
        bb = (uint32_t)x0 | ((uint32_t)x1 << 8) |
             ((uint32_t)y0 << 16) | ((uint32_t)y1 << 24);

    gdat[t * 2 + 0] = make_float4(mx, my, -0.5f * ca, -cb);
    gdat[t * 2 + 1] = make_float4(-0.5f * cc, op, cr, cg);
    gblue[t] = cbl;
    gbbox[t] = bb;
    gkey[t]  = ((unsigned long long)__float_as_uint(dep) << 13) | (unsigned)g;
}

// ---------------------------------------------------------------------------
// Kernel 2: per-tile build+sort+composite. 256 threads (4 waves) per 8x8 tile
// (2048 blocks). Wave q composites depth-quarter q of the sorted list over all
// 64 pixels; quarters merge associatively at the end.
//  1. scan 8192 bboxes (4 passes x 8 register-prefetched chunks, LDS-atomic
//     compaction; key64 = (depth<<23)|(g<<10)|slot keeps data slot with key)
//  2. staging gather issued into REGISTERS pre-sort; ds_write post-sort ->
//     L2 latency hides under the sort (all barriers are lgkmcnt-only LDS_BAR,
//     no vmcnt drain)
//  3. sort: per-wave shfl_xor bitonic on 64-blocks, LDS bitonic k>=128
//  4. composite quarter [lo,hi), broadcast LDS reads, per-wave early exit
//     (T<1e-4; truncation error bound 1e-4 << 2e-2 threshold)
//  5. merge: c = c0 + T0(c1 + T1(c2 + T2*c3)), T = T0*T1*T2*T3
// ---------------------------------------------------------------------------
__global__ __launch_bounds__(256) void raster(
    const float4* __restrict__ gdat, const float* __restrict__ gblue,
    const uint32_t* __restrict__ gbbox, const unsigned long long* __restrict__ gkey,
    float* __restrict__ out)
{
    __shared__ unsigned long long keys[MAXLIST];   // 4 KB
    __shared__ float4 sdat[MAXLIST][2];            // 16 KB
    __shared__ float  sblue[MAXLIST];              // 2 KB
    __shared__ float4 xch[3][64];                  // 3 KB
    __shared__ int    scnt;

    const int tid  = threadIdx.x;       // 0..255
    const int lane = tid & 63;
    const int wid  = tid >> 6;          // 0..3
    const int tx = blockIdx.x, ty = blockIdx.y, b = blockIdx.z;
    const int bg = b * GCOUNT;

    if (tid == 0) scnt = 0;
    LDS_BAR();

    // ---- 1. scan & compact (unordered; sort fixes order) ----
    const unsigned long long mlt = (1ull << lane) - 1ull;
    for (int outer = 0; outer < GCOUNT; outer += 2048) {
        uint32_t v[8];
#pragma unroll
        for (int k = 0; k < 8; ++k)
            v[k] = gbbox[bg + outer + k * 256 + tid];
        bool hit[8];
        unsigned long long bal[8];
        int cnts[8], sum = 0;
#pragma unroll
        for (int k = 0; k < 8; ++k) {
            const int x0 = v[k] & 0xFF, x1 = (v[k] >> 8) & 0xFF;
            const int y0 = (v[k] >> 16) & 0xFF, y1 = (v[k] >> 24) & 0xFF;
            hit[k] = (tx >= x0) & (tx <= x1) & (ty >= y0) & (ty <= y1);
            bal[k] = __ballot(hit[k]);
            cnts[k] = __popcll(bal[k]);
            sum += cnts[k];
        }
        int wbase = 0;
        if (lane == 0 && sum) wbase = atomicAdd(&scnt, sum);
        wbase = __shfl(wbase, 0);
#pragma unroll
        for (int k = 0; k < 8; ++k) {
            if (hit[k]) {
                const int pos = wbase + __popcll(bal[k] & mlt);
                if (pos < MAXLIST)
                    keys[pos] = (gkey[bg + outer + k * 256 + tid] << 10) |
                                (unsigned)pos;
            }
            wbase += cnts[k];
        }
    }
    LDS_BAR();
    const int cnt = min(scnt, MAXLIST);

    // ---- 2. staging gather -> registers (ds_write deferred to post-sort) ----
    const int i0 = tid, i1 = tid + 256;
    const bool h0 = i0 < cnt, h1 = i1 < cnt;
    float4 r0a, r0b, r1a, r1b;
    float r0c = 0.f, r1c = 0.f;
    if (h0) {
        const int g0 = (int)((keys[i0] >> 10) & 8191);
        r0a = gdat[(bg + g0) * 2 + 0];
        r0b = gdat[(bg + g0) * 2 + 1];
        r0c = gblue[bg + g0];
    }
    if (h1) {
        const int g1 = (int)((keys[i1] >> 10) & 8191);
        r1a = gdat[(bg + g1) * 2 + 0];
        r1b = gdat[(bg + g1) * 2 + 1];
        r1c = gblue[bg + g1];
    }

    // ---- 3. sort keys[0..cnt) ascending ----
    int P = 64;
    while (P < cnt) P <<= 1;
    for (int i = cnt + tid; i < P; i += 256) keys[i] = ~0ull;
    LDS_BAR();

    // per-wave in-register bitonic over each 64-block (levels k=2..64)
    for (int bi = wid; (bi << 6) < P; bi += 4) {
        unsigned long long key = keys[(bi << 6) | lane];
        const bool descBlock = (bi & 1);   // odd blocks descending
#pragma unroll
        for (int k = 2; k <= 64; k <<= 1) {
            for (int j = k >> 1; j > 0; j >>= 1) {
                const unsigned long long other = __shfl_xor(key, j);
                const bool asc   = (((lane & k) == 0) != descBlock);
                const bool lower = ((lane & j) == 0);
                const unsigned long long mn = (key < other) ? key : other;
                const unsigned long long mx = (key < other) ? other : key;
                key = (asc == lower) ? mn : mx;
            }
        }
        keys[(bi << 6) | lane] = key;
    }
    LDS_BAR();

    // LDS bitonic stages, levels k=128..P
    for (int k = 128; k <= P; k <<= 1) {
        for (int j = k >> 1; j > 0; j >>= 1) {
            for (int i = tid; i < P; i += 256) {
                const int ixj = i ^ j;
                if (ixj > i) {
                    const unsigned long long A = keys[i], Bv = keys[ixj];
                    const bool asc = ((i & k) == 0);
                    if ((A > Bv) == asc) { keys[i] = Bv; keys[ixj] = A; }
                }
            }
            LDS_BAR();
        }
    }

    // ---- staged data lands in LDS (vmcnt waited here, hidden by sort) ----
    if (h0) { sdat[i0][0] = r0a; sdat[i0][1] = r0b; sblue[i0] = r0c; }
    if (h1) { sdat[i1][0] = r1a; sdat[i1][1] = r1b; sblue[i1] = r1c; }
    LDS_BAR();

    // ---- 4. composite quarter [lo,hi) over all 64 pixels ----
    const int px = tx * TILE + (lane & 7);
    const int py = ty * TILE + (lane >> 3);
    const float pxf = px + 0.5f, pyf = py + 0.5f;
    const int lo = (cnt * wid) >> 2;
    const int hi = (cnt * (wid + 1)) >> 2;

    float T = 1.0f, ir = 0.f, ig = 0.f, ib = 0.f;

    for (int s = lo; s < hi; ++s) {
        const int slot = (int)(keys[s] & 1023u);
        const float4 a0 = sdat[slot][0];
        const float4 a1 = sdat[slot][1];
        const float  bl = sblue[slot];
        const float dx = pxf - a0.x, dy = pyf - a0.y;
        float pw = a0.z * dx * dx + a1.x * dy * dy + a0.w * dx * dy;
        pw = fminf(pw, 0.0f);
        float al = a1.y * __expf(pw);
        al = fminf(al, 0.999f);
        if (al >= (1.0f / 255.0f)) {
            const float w = T * al;
            ir += w * a1.z;
            ig += w * a1.w;
            ib += w * bl;
            T -= w;
        }
        if (((s - lo) & 7) == 7 && !__any(T >= 1e-4f)) break;
    }

    // ---- 5. merge quarters ----
    if (wid) xch[wid - 1][lane] = make_float4(ir, ig, ib, T);
    LDS_BAR();
    if (wid == 0) {
        const float4 c1 = xch[0][lane];
        const float4 c2 = xch[1][lane];
        const float4 c3 = xch[2][lane];
        float rx = c2.x + c2.w * c3.x;
        float ry = c2.y + c2.w * c3.y;
        float rz = c2.z + c2.w * c3.z;
        float rw = c2.w * c3.w;
        rx = c1.x + c1.w * rx;
        ry = c1.y + c1.w * ry;
        rz = c1.z + c1.w * rz;
        rw = c1.w * rw;
        ir += T * rx;
        ig += T * ry;
        ib += T * rz;
        T  *= rw;
        const int pix = (b * IMGH + py) * IMGW + px;
        out[pix * 3 + 0] = ir;
        out[pix * 3 + 1] = ig;
        out[pix * 3 + 2] = ib;
        out[(size_t)BATCH * IMGH * IMGW * 3 + pix] = 1.0f - T;
    }
}

extern "C" void kernel_launch(void* const* d_in, const int* in_sizes, int n_in,
                              void* d_out, int out_size, void* d_ws, size_t ws_size,
                              hipStream_t stream) {
    const float* means  = (const float*)d_in[0];
    const float* conics = (const float*)d_in[1];
    const float* colors = (const float*)d_in[2];
    const float* opac   = (const float*)d_in[3];
    const float* depths = (const float*)d_in[4];
    // d_in[5], d_in[6]: image_height/width == 256, hardcoded.

    char* ws = (char*)d_ws;
    const size_t NG = (size_t)BATCH * GCOUNT;
    float4*             gdat  = (float4*)ws;                         // 32B * NG
    float*              gblue = (float*)(ws + NG * 32);              // 4B * NG
    uint32_t*           gbbox = (uint32_t*)(ws + NG * 36);           // 4B * NG
    unsigned long long* gkey  = (unsigned long long*)(ws + NG * 40); // 8B * NG
    float* out = (float*)d_out;

    hipLaunchKernelGGL(prep, dim3((BATCH * GCOUNT + 255) / 256), dim3(256), 0, stream,
                       means, conics, colors, opac, depths, gdat, gblue, gbbox, gkey);
    hipLaunchKernelGGL(raster, dim3(TILES_X, TILES_Y, BATCH), dim3(256), 0, stream,
                       gdat, gblue, gbbox, gkey, out);
}

// Round 6
// 35.566 us; speedup vs baseline: 1.3450x; 1.3450x over previous
//
#include <hip/hip_runtime.h>
#include <stdint.h>

#define GCOUNT 8192
#define BATCH 2
#define IMGH 256
#define IMGW 256
#define TILE 16
#define TILES_X (IMGW / TILE)   // 16
#define TILES_Y (IMGH / TILE)   // 16
#define MAXLIST 1024            // avg ~250 survivors per 16x16 tile (R2: uncapped == capped)

// Barrier that does NOT drain vmcnt (unlike __syncthreads): LDS ordering only.
// Keeps the staging global-loads in flight across the whole sort phase.
#define LDS_BAR() do { asm volatile("s_waitcnt lgkmcnt(0)" ::: "memory"); \
                       __builtin_amdgcn_s_barrier(); } while (0)

// ---------------------------------------------------------------------------
// Kernel 1: per-Gaussian prep. Repack into composite-ready form + conservative
// 16px-tile bbox + stable sort key (depth_bits<<13 | idx): depths positive so
// IEEE bits are order-preserving; low 13 bits = stable tie-break == jnp.argsort.
// ---------------------------------------------------------------------------
__global__ __launch_bounds__(256) void prep(
    const float* __restrict__ means, const float* __restrict__ conics,
    const float* __restrict__ colors, const float* __restrict__ opac,
    const float* __restrict__ depths,
    float4* __restrict__ gdat,            // [B*G*2]: (mx,my,-a/2,-b) (-c/2,op,r,g)
    float* __restrict__ gblue,            // [B*G]
    uint32_t* __restrict__ gbbox,         // [B*G]
    unsigned long long* __restrict__ gkey)// [B*G]
{
    const int t = blockIdx.x * 256 + threadIdx.x;
    if (t >= BATCH * GCOUNT) return;
    const int g = t & (GCOUNT - 1);

    const float mx  = means[t * 2 + 0];
    const float my  = means[t * 2 + 1];
    const float ca  = conics[t * 3 + 0];
    const float cb  = conics[t * 3 + 1];
    const float cc  = conics[t * 3 + 2];
    const float cr  = colors[t * 3 + 0];
    const float cg  = colors[t * 3 + 1];
    const float cbl = colors[t * 3 + 2];
    const float op  = opac[t];
    const float dep = depths[t];

    // alpha >= 1/255  <=>  Q(d) <= ln(255*op) = tt  (op >= 0.05 so tt > 0)
    const float tt  = __logf(255.0f * op);
    const float det = ca * cc - cb * cb;   // >= 0.75*a*c > 0
    const float inv = 2.0f * tt / det;
    const float dxm = sqrtf(inv * cc) + 1.0f;  // +1px safety pad
    const float dym = sqrtf(inv * ca) + 1.0f;

    int x0 = max(0, (int)floorf((mx - dxm) * (1.0f / TILE)));
    int x1 = min(TILES_X - 1, (int)floorf((mx + dxm) * (1.0f / TILE)));
    int y0 = max(0, (int)floorf((my - dym) * (1.0f / TILE)));
    int y1 = min(TILES_Y - 1, (int)floorf((my + dym) * (1.0f / TILE)));
    uint32_t bb;
    if (x1 < x0 || y1 < y0)
        bb = 0xFFu;  // x0=255 never matches (tx <= 15)
    else
        bb = (uint32_t)x0 | ((uint32_t)x1 << 8) |
             ((uint32_t)y0 << 16) | ((uint32_t)y1 << 24);

    gdat[t * 2 + 0] = make_float4(mx, my, -0.5f * ca, -cb);
    gdat[t * 2 + 1] = make_float4(-0.5f * cc, op, cr, cg);
    gblue[t] = cbl;
    gbbox[t] = bb;
    gkey[t]  = ((unsigned long long)__float_as_uint(dep) << 13) | (unsigned)g;
}

// ---------------------------------------------------------------------------
// Kernel 2: per-tile build+sort+composite. 1024 threads (16 waves) per 16x16
// tile, 512 blocks = 2 blocks/CU = 100% occupancy cap (LDS 56.3KB, VGPR<=64).
// Waves form 4 depth-segments x 4 pixel-waves (64px each); segments merge
// associatively (c = c_f + T_f*c_b, T = T_f*T_b).
//  1. scan 8192 bboxes (8 register-prefetched chunks, LDS-atomic compaction;
//     key64 = (depth<<23)|(g<<10)|slot keeps the data slot with the key)
//  2. staging gather into REGISTERS pre-sort; ds_write post-sort -> L2
//     latency hides under the sort (all barriers lgkmcnt-only, no vmcnt drain)
//  3. sort: per-wave shfl_xor bitonic on 64-blocks; for k>=128 LDS stages for
//     j>=64 + in-register shfl finish for j<=32 (few barriers)
//  4. composite segment [lo,hi), broadcast LDS reads, per-wave early exit
//     (T<1e-4; truncation error <= 4e-4 << 2e-2 threshold)
//  5. merge segments via LDS, segment-0 waves write out.
// ---------------------------------------------------------------------------
__global__ __launch_bounds__(1024, 8) void raster(
    const float4* __restrict__ gdat, const float* __restrict__ gblue,
    const uint32_t* __restrict__ gbbox, const unsigned long long* __restrict__ gkey,
    float* __restrict__ out)
{
    __shared__ unsigned long long keys[MAXLIST];   // 8 KB
    __shared__ float4 sdat[MAXLIST][2];            // 32 KB
    __shared__ float  sblue[MAXLIST];              // 4 KB
    __shared__ float4 xch[3][256];                 // 12 KB
    __shared__ int    scnt;

    const int tid  = threadIdx.x;       // 0..1023
    const int lane = tid & 63;
    const int wid  = tid >> 6;          // 0..15
    const int tx = blockIdx.x, ty = blockIdx.y, b = blockIdx.z;
    const int bg = b * GCOUNT;

    if (tid == 0) scnt = 0;
    LDS_BAR();

    // ---- 1. scan & compact (unordered; sort fixes order) ----
    const unsigned long long mlt = (1ull << lane) - 1ull;
    {
        uint32_t v[8];
#pragma unroll
        for (int k = 0; k < 8; ++k)
            v[k] = gbbox[bg + k * 1024 + tid];
        bool hit[8];
        unsigned long long bal[8];
        int cnts[8], sum = 0;
#pragma unroll
        for (int k = 0; k < 8; ++k) {
            const int x0 = v[k] & 0xFF, x1 = (v[k] >> 8) & 0xFF;
            const int y0 = (v[k] >> 16) & 0xFF, y1 = (v[k] >> 24) & 0xFF;
            hit[k] = (tx >= x0) & (tx <= x1) & (ty >= y0) & (ty <= y1);
            bal[k] = __ballot(hit[k]);
            cnts[k] = __popcll(bal[k]);
            sum += cnts[k];
        }
        int wbase = 0;
        if (lane == 0 && sum) wbase = atomicAdd(&scnt, sum);
        wbase = __shfl(wbase, 0);
#pragma unroll
        for (int k = 0; k < 8; ++k) {
            if (hit[k]) {
                const int pos = wbase + __popcll(bal[k] & mlt);
                if (pos < MAXLIST)
                    keys[pos] = (gkey[bg + k * 1024 + tid] << 10) | (unsigned)pos;
            }
            wbase += cnts[k];
        }
    }
    LDS_BAR();
    const int cnt = min(scnt, MAXLIST);

    // ---- 2. staging gather -> registers (ds_write deferred to post-sort) ----
    const bool h0 = tid < cnt;
    float4 r0a, r0b;
    float r0c = 0.f;
    if (h0) {
        const int g0 = (int)((keys[tid] >> 10) & 8191);
        r0a = gdat[(bg + g0) * 2 + 0];
        r0b = gdat[(bg + g0) * 2 + 1];
        r0c = gblue[bg + g0];
    }

    // ---- 3. sort keys[0..cnt) ascending ----
    int P = 64;
    while (P < cnt) P <<= 1;
    for (int i = cnt + tid; i < P; i += 1024) keys[i] = ~0ull;
    LDS_BAR();

    // per-wave in-register bitonic over each 64-block (levels k=2..64)
    if ((wid << 6) < P) {
        unsigned long long key = keys[(wid << 6) | lane];
        const bool descBlock = (wid & 1);   // odd blocks descending
#pragma unroll
        for (int k = 2; k <= 64; k <<= 1) {
            for (int j = k >> 1; j > 0; j >>= 1) {
                const unsigned long long other = __shfl_xor(key, j);
                const bool asc   = (((lane & k) == 0) != descBlock);
                const bool lower = ((lane & j) == 0);
                const unsigned long long mn = (key < other) ? key : other;
                const unsigned long long mx = (key < other) ? other : key;
                key = (asc == lower) ? mn : mx;
            }
        }
        keys[(wid << 6) | lane] = key;
    }
    LDS_BAR();

    // levels k=128..P: LDS stages for j>=64, in-register shfl finish j<=32
    for (int k = 128; k <= P; k <<= 1) {
        for (int j = k >> 1; j >= 64; j >>= 1) {
            const int i = tid;
            if (i < P) {
                const int ixj = i ^ j;
                if (ixj > i) {
                    const unsigned long long A = keys[i], Bv = keys[ixj];
                    const bool asc = ((i & k) == 0);
                    if ((A > Bv) == asc) { keys[i] = Bv; keys[ixj] = A; }
                }
            }
            LDS_BAR();
        }
        if ((wid << 6) < P) {
            const int base = wid << 6;
            unsigned long long key = keys[base | lane];
            const bool asc = ((base & k) == 0);   // uniform per 64-block (k>=128)
#pragma unroll
            for (int j = 32; j > 0; j >>= 1) {
                const unsigned long long other = __shfl_xor(key, j);
                const bool lower = ((lane & j) == 0);
                const unsigned long long mn = (key < other) ? key : other;
                const unsigned long long mx = (key < other) ? other : key;
                key = (asc == lower) ? mn : mx;
            }
            keys[base | lane] = key;
        }
        LDS_BAR();
    }

    // ---- staged data lands in LDS (vmcnt waited here, hidden by sort) ----
    if (h0) { sdat[tid][0] = r0a; sdat[tid][1] = r0b; sblue[tid] = r0c; }
    LDS_BAR();

    // ---- 4. composite segment [lo,hi) over this wave's 64 pixels ----
    const int seg = wid >> 2;              // depth segment 0..3
    const int p   = ((wid & 3) << 6) | lane; // pixel 0..255
    const int px = tx * TILE + (p & 15);
    const int py = ty * TILE + (p >> 4);
    const float pxf = px + 0.5f, pyf = py + 0.5f;
    const int lo = (cnt * seg) >> 2;
    const int hi = (cnt * (seg + 1)) >> 2;

    float T = 1.0f, ir = 0.f, ig = 0.f, ib = 0.f;

    for (int s = lo; s < hi; ++s) {
        const int slot = (int)(keys[s] & 1023u);
        const float4 a0 = sdat[slot][0];
        const float4 a1 = sdat[slot][1];
        const float  bl = sblue[slot];
        const float dx = pxf - a0.x, dy = pyf - a0.y;
        float pw = a0.z * dx * dx + a1.x * dy * dy + a0.w * dx * dy;
        pw = fminf(pw, 0.0f);
        float al = a1.y * __expf(pw);
        al = fminf(al, 0.999f);
        if (al >= (1.0f / 255.0f)) {
            const float w = T * al;
            ir += w * a1.z;
            ig += w * a1.w;
            ib += w * bl;
            T -= w;
        }
        if (((s - lo) & 7) == 7 && !__any(T >= 1e-4f)) break;
    }

    // ---- 5. merge segments: c = c0 + T0(c1 + T1(c2 + T2*c3)) ----
    if (seg) xch[seg - 1][p] = make_float4(ir, ig, ib, T);
    LDS_BAR();
    if (seg == 0) {
#pragma unroll
        for (int q = 0; q < 3; ++q) {
            const float4 c = xch[q][p];
            ir += T * c.x;
            ig += T * c.y;
            ib += T * c.z;
            T  *= c.w;
        }
        const int pix = (b * IMGH + py) * IMGW + px;
        out[pix * 3 + 0] = ir;
        out[pix * 3 + 1] = ig;
        out[pix * 3 + 2] = ib;
        out[(size_t)BATCH * IMGH * IMGW * 3 + pix] = 1.0f - T;
    }
}

extern "C" void kernel_launch(void* const* d_in, const int* in_sizes, int n_in,
                              void* d_out, int out_size, void* d_ws, size_t ws_size,
                              hipStream_t stream) {
    const float* means  = (const float*)d_in[0];
    const float* conics = (const float*)d_in[1];
    const float* colors = (const float*)d_in[2];
    const float* opac   = (const float*)d_in[3];
    const float* depths = (const float*)d_in[4];
    // d_in[5], d_in[6]: image_height/width == 256, hardcoded.

    char* ws = (char*)d_ws;
    const size_t NG = (size_t)BATCH * GCOUNT;
    float4*             gdat  = (float4*)ws;                         // 32B * NG
    float*              gblue = (float*)(ws + NG * 32);              // 4B * NG
    uint32_t*           gbbox = (uint32_t*)(ws + NG * 36);           // 4B * NG
    unsigned long long* gkey  = (unsigned long long*)(ws + NG * 40); // 8B * NG
    float* out = (float*)d_out;

    hipLaunchKernelGGL(prep, dim3((BATCH * GCOUNT + 255) / 256), dim3(256), 0, stream,
                       means, conics, colors, opac, depths, gdat, gblue, gbbox, gkey);
    hipLaunchKernelGGL(raster, dim3(TILES_X, TILES_Y, BATCH), dim3(1024), 0, stream,
                       gdat, gblue, gbbox, gkey, out);
}

// Round 7
// 32.431 us; speedup vs baseline: 1.4750x; 1.0967x over previous
//
#include <hip/hip_runtime.h>
#include <stdint.h>

#define GCOUNT 8192
#define BATCH 2
#define IMGH 256
#define IMGW 256
#define TILE 16
#define TILES_X (IMGW / TILE)   // 16
#define TILES_Y (IMGH / TILE)   // 16
#define MAXLIST 1024            // avg ~250 survivors per 16x16 tile (R2: uncapped == capped)

// Barrier that does NOT drain vmcnt (unlike __syncthreads): LDS ordering only.
// Keeps the staging global-loads in flight across the whole sort phase.
#define LDS_BAR() do { asm volatile("s_waitcnt lgkmcnt(0)" ::: "memory"); \
                       __builtin_amdgcn_s_barrier(); } while (0)

// ---------------------------------------------------------------------------
// Kernel 1: per-Gaussian prep. Repack into composite-ready form + conservative
// 16px-tile bbox + stable sort key (depth_bits<<13 | idx): depths positive so
// IEEE bits are order-preserving; low 13 bits = stable tie-break == jnp.argsort.
// ---------------------------------------------------------------------------
__global__ __launch_bounds__(256) void prep(
    const float* __restrict__ means, const float* __restrict__ conics,
    const float* __restrict__ colors, const float* __restrict__ opac,
    const float* __restrict__ depths,
    float4* __restrict__ gdat,            // [B*G*2]: (mx,my,-a/2,-b) (-c/2,op,r,g)
    float* __restrict__ gblue,            // [B*G]
    uint32_t* __restrict__ gbbox,         // [B*G]
    unsigned long long* __restrict__ gkey)// [B*G]
{
    const int t = blockIdx.x * 256 + threadIdx.x;
    if (t >= BATCH * GCOUNT) return;
    const int g = t & (GCOUNT - 1);

    const float mx  = means[t * 2 + 0];
    const float my  = means[t * 2 + 1];
    const float ca  = conics[t * 3 + 0];
    const float cb  = conics[t * 3 + 1];
    const float cc  = conics[t * 3 + 2];
    const float cr  = colors[t * 3 + 0];
    const float cg  = colors[t * 3 + 1];
    const float cbl = colors[t * 3 + 2];
    const float op  = opac[t];
    const float dep = depths[t];

    // alpha >= 1/255  <=>  Q(d) <= ln(255*op) = tt  (op >= 0.05 so tt > 0)
    const float tt  = __logf(255.0f * op);
    const float det = ca * cc - cb * cb;   // >= 0.75*a*c > 0
    const float inv = 2.0f * tt / det;
    const float dxm = sqrtf(inv * cc) + 1.0f;  // +1px safety pad
    const float dym = sqrtf(inv * ca) + 1.0f;

    int x0 = max(0, (int)floorf((mx - dxm) * (1.0f / TILE)));
    int x1 = min(TILES_X - 1, (int)floorf((mx + dxm) * (1.0f / TILE)));
    int y0 = max(0, (int)floorf((my - dym) * (1.0f / TILE)));
    int y1 = min(TILES_Y - 1, (int)floorf((my + dym) * (1.0f / TILE)));
    uint32_t bb;
    if (x1 < x0 || y1 < y0)
        bb = 0xFFu;  // x0=255 never matches (tx <= 15)
    else
        bb = (uint32_t)x0 | ((uint32_t)x1 << 8) |
             ((uint32_t)y0 << 16) | ((uint32_t)y1 << 24);

    gdat[t * 2 + 0] = make_float4(mx, my, -0.5f * ca, -cb);
    gdat[t * 2 + 1] = make_float4(-0.5f * cc, op, cr, cg);
    gblue[t] = cbl;
    gbbox[t] = bb;
    gkey[t]  = ((unsigned long long)__float_as_uint(dep) << 13) | (unsigned)g;
}

// ---------------------------------------------------------------------------
// Kernel 2: per-tile build+sort+composite. 1024 threads (16 waves) per 16x16
// tile, 512 blocks = 2 blocks/CU. Waves = 8 depth-segments x 2 pixel-groups;
// each lane owns an ADJACENT PIXEL PAIR (one broadcast record read serves 2
// pixels -> half the wave-iters; pw1 is a 3-op incremental update of pw0).
//  1. scan 8192 bboxes (8 register-prefetched chunks, LDS-atomic compaction;
//     key64 = (depth<<23)|(g<<10)|slot keeps the compact slot with the key)
//  2. staging gather into REGISTERS pre-sort; lands in LDS post-sort -> L2
//     latency hides under the sort (all barriers lgkmcnt-only, no vmcnt drain)
//  3. sort: per-wave shfl_xor bitonic on 64-blocks; k>=128 LDS stages (j>=64)
//     + in-register shfl finish (j<=32)
//  4. physical reorder: inv[slot]=sortedpos, scatter staged regs into depth
//     order -> composite reads sdat[s] SEQUENTIALLY (3 LDS instr/iter, no
//     key read, no slot math)
//  5. composite segment, per-wave early exit (T<1e-4; error <= 8e-4 << 2e-2)
//  6. merge 8 segments associatively; segment-0 waves write float2 pairs.
// ---------------------------------------------------------------------------
__global__ __launch_bounds__(1024, 8) void raster(
    const float4* __restrict__ gdat, const float* __restrict__ gblue,
    const uint32_t* __restrict__ gbbox, const unsigned long long* __restrict__ gkey,
    float* __restrict__ out)
{
    __shared__ unsigned long long keys[MAXLIST];   // 8 KB
    __shared__ float4 sdat[MAXLIST][2];            // 32 KB
    __shared__ float  sblue[MAXLIST];              // 4 KB
    __shared__ uint16_t sinv[MAXLIST];             // 2 KB
    __shared__ float4 xch[7][256];                 // 28 KB
    __shared__ int    scnt;

    const int tid  = threadIdx.x;       // 0..1023
    const int lane = tid & 63;
    const int wid  = tid >> 6;          // 0..15
    const int tx = blockIdx.x, ty = blockIdx.y, b = blockIdx.z;
    const int bg = b * GCOUNT;

    if (tid == 0) scnt = 0;
    LDS_BAR();

    // ---- 1. scan & compact (unordered; sort fixes order) ----
    const unsigned long long mlt = (1ull << lane) - 1ull;
    {
        uint32_t v[8];
#pragma unroll
        for (int k = 0; k < 8; ++k)
            v[k] = gbbox[bg + k * 1024 + tid];
        bool hit[8];
        unsigned long long bal[8];
        int cnts[8], sum = 0;
#pragma unroll
        for (int k = 0; k < 8; ++k) {
            const int x0 = v[k] & 0xFF, x1 = (v[k] >> 8) & 0xFF;
            const int y0 = (v[k] >> 16) & 0xFF, y1 = (v[k] >> 24) & 0xFF;
            hit[k] = (tx >= x0) & (tx <= x1) & (ty >= y0) & (ty <= y1);
            bal[k] = __ballot(hit[k]);
            cnts[k] = __popcll(bal[k]);
            sum += cnts[k];
        }
        int wbase = 0;
        if (lane == 0 && sum) wbase = atomicAdd(&scnt, sum);
        wbase = __shfl(wbase, 0);
#pragma unroll
        for (int k = 0; k < 8; ++k) {
            if (hit[k]) {
                const int pos = wbase + __popcll(bal[k] & mlt);
                if (pos < MAXLIST)
                    keys[pos] = (gkey[bg + k * 1024 + tid] << 10) | (unsigned)pos;
            }
            wbase += cnts[k];
        }
    }
    LDS_BAR();
    const int cnt = min(scnt, MAXLIST);

    // ---- 2. staging gather -> registers (LDS landing deferred past sort) ----
    const bool h0 = tid < cnt;
    float4 r0a, r0b;
    float r0c = 0.f;
    if (h0) {
        const int g0 = (int)((keys[tid] >> 10) & 8191);
        r0a = gdat[(bg + g0) * 2 + 0];
        r0b = gdat[(bg + g0) * 2 + 1];
        r0c = gblue[bg + g0];
    }

    // ---- 3. sort keys[0..cnt) ascending ----
    int P = 64;
    while (P < cnt) P <<= 1;
    for (int i = cnt + tid; i < P; i += 1024) keys[i] = ~0ull;
    LDS_BAR();

    // per-wave in-register bitonic over each 64-block (levels k=2..64)
    if ((wid << 6) < P) {
        unsigned long long key = keys[(wid << 6) | lane];
        const bool descBlock = (wid & 1);   // odd blocks descending
#pragma unroll
        for (int k = 2; k <= 64; k <<= 1) {
            for (int j = k >> 1; j > 0; j >>= 1) {
                const unsigned long long other = __shfl_xor(key, j);
                const bool asc   = (((lane & k) == 0) != descBlock);
                const bool lower = ((lane & j) == 0);
                const unsigned long long mn = (key < other) ? key : other;
                const unsigned long long mx = (key < other) ? other : key;
                key = (asc == lower) ? mn : mx;
            }
        }
        keys[(wid << 6) | lane] = key;
    }
    LDS_BAR();

    // levels k=128..P: LDS stages for j>=64, in-register shfl finish j<=32
    for (int k = 128; k <= P; k <<= 1) {
        for (int j = k >> 1; j >= 64; j >>= 1) {
            const int i = tid;
            if (i < P) {
                const int ixj = i ^ j;
                if (ixj > i) {
                    const unsigned long long A = keys[i], Bv = keys[ixj];
                    const bool asc = ((i & k) == 0);
                    if ((A > Bv) == asc) { keys[i] = Bv; keys[ixj] = A; }
                }
            }
            LDS_BAR();
        }
        if ((wid << 6) < P) {
            const int base = wid << 6;
            unsigned long long key = keys[base | lane];
            const bool asc = ((base & k) == 0);   // uniform per 64-block (k>=128)
#pragma unroll
            for (int j = 32; j > 0; j >>= 1) {
                const unsigned long long other = __shfl_xor(key, j);
                const bool lower = ((lane & j) == 0);
                const unsigned long long mn = (key < other) ? key : other;
                const unsigned long long mx = (key < other) ? other : key;
                key = (asc == lower) ? mn : mx;
            }
            keys[base | lane] = key;
        }
        LDS_BAR();
    }

    // ---- 4. physical reorder: records land in LDS in DEPTH ORDER ----
    for (int i = tid; i < cnt; i += 1024)
        sinv[(int)(keys[i] & 1023u)] = (uint16_t)i;
    LDS_BAR();
    if (h0) {   // vmcnt for r0* waited here by compiler, hidden under the sort
        const int q = sinv[tid];
        sdat[q][0] = r0a;
        sdat[q][1] = r0b;
        sblue[q]   = r0c;
    }
    LDS_BAR();

    // ---- 5. composite segment: lane owns pixel pair (p0, p0+1) ----
    const int seg = wid >> 1;                   // 0..7
    const int grp = wid & 1;                    // 0..1
    const int p0  = (grp << 7) | (lane << 1);   // even pixel 0..254
    const int px0 = tx * TILE + (p0 & 15);
    const int py  = ty * TILE + (p0 >> 4);
    const float pxf = px0 + 0.5f, pyf = py + 0.5f;
    const int lo = (cnt * seg) >> 3;
    const int hi = (cnt * (seg + 1)) >> 3;

    float T0 = 1.f, ir0 = 0.f, ig0 = 0.f, ib0 = 0.f;
    float T1 = 1.f, ir1 = 0.f, ig1 = 0.f, ib1 = 0.f;

    for (int s = lo; s < hi; ++s) {
        const float4 a0 = sdat[s][0];
        const float4 a1 = sdat[s][1];
        const float  bl = sblue[s];
        const float dx = pxf - a0.x, dy = pyf - a0.y;
        // pw0 = qa*dx^2 + qc*dy^2 + qb*dx*dy   (qa=a0.z, qb=a0.w, qc=a1.x)
        const float qbdy = a0.w * dy;
        float pw0 = a0.z * dx * dx;
        pw0 = fmaf(a1.x * dy, dy, pw0);
        pw0 = fmaf(qbdy, dx, pw0);
        // pw1 = pw(dx+1,dy) = pw0 + qa*(2dx+1) + qb*dy
        float pw1 = fmaf(a0.z, fmaf(2.f, dx, 1.f), pw0 + qbdy);
        pw0 = fminf(pw0, 0.f);
        pw1 = fminf(pw1, 0.f);
        float al0 = fminf(a1.y * __expf(pw0), 0.999f);
        float al1 = fminf(a1.y * __expf(pw1), 0.999f);
        if (al0 >= (1.0f / 255.0f)) {
            const float w = T0 * al0;
            ir0 += w * a1.z; ig0 += w * a1.w; ib0 += w * bl;
            T0 -= w;
        }
        if (al1 >= (1.0f / 255.0f)) {
            const float w = T1 * al1;
            ir1 += w * a1.z; ig1 += w * a1.w; ib1 += w * bl;
            T1 -= w;
        }
        if (((s - lo) & 7) == 7 && !__any(fmaxf(T0, T1) >= 1e-4f)) break;
    }

    // ---- 6. merge segments: c = c0 + T0(c1 + T1(...)) ----
    if (seg) {
        xch[seg - 1][p0]     = make_float4(ir0, ig0, ib0, T0);
        xch[seg - 1][p0 | 1] = make_float4(ir1, ig1, ib1, T1);
    }
    LDS_BAR();
    if (seg == 0) {
#pragma unroll
        for (int q = 0; q < 7; ++q) {
            const float4 c = xch[q][p0];
            ir0 += T0 * c.x; ig0 += T0 * c.y; ib0 += T0 * c.z; T0 *= c.w;
            const float4 d = xch[q][p0 | 1];
            ir1 += T1 * d.x; ig1 += T1 * d.y; ib1 += T1 * d.z; T1 *= d.w;
        }
        const int pix0 = (b * IMGH + py) * IMGW + px0;
        *(float2*)&out[pix0 * 3 + 0] = make_float2(ir0, ig0);
        *(float2*)&out[pix0 * 3 + 2] = make_float2(ib0, ir1);
        *(float2*)&out[pix0 * 3 + 4] = make_float2(ig1, ib1);
        *(float2*)&out[(size_t)BATCH * IMGH * IMGW * 3 + pix0] =
            make_float2(1.0f - T0, 1.0f - T1);
    }
}

extern "C" void kernel_launch(void* const* d_in, const int* in_sizes, int n_in,
                              void* d_out, int out_size, void* d_ws, size_t ws_size,
                              hipStream_t stream) {
    const float* means  = (const float*)d_in[0];
    const float* conics = (const float*)d_in[1];
    const float* colors = (const float*)d_in[2];
    const float* opac   = (const float*)d_in[3];
    const float* depths = (const float*)d_in[4];
    // d_in[5], d_in[6]: image_height/width == 256, hardcoded.

    char* ws = (char*)d_ws;
    const size_t NG = (size_t)BATCH * GCOUNT;
    float4*             gdat  = (float4*)ws;                         // 32B * NG
    float*              gblue = (float*)(ws + NG * 32);              // 4B * NG
    uint32_t*           gbbox = (uint32_t*)(ws + NG * 36);           // 4B * NG
    unsigned long long* gkey  = (unsigned long long*)(ws + NG * 40); // 8B * NG
    float* out = (float*)d_out;

    hipLaunchKernelGGL(prep, dim3((BATCH * GCOUNT + 255) / 256), dim3(256), 0, stream,
                       means, conics, colors, opac, depths, gdat, gblue, gbbox, gkey);
    hipLaunchKernelGGL(raster, dim3(TILES_X, TILES_Y, BATCH), dim3(1024), 0, stream,
                       gdat, gblue, gbbox, gkey, out);
}